// Round 6
// baseline (30.495 us; speedup 1.0000x reference)
//
#include <hip/hip_runtime.h>

#define H 512
#define W 512
#define N (H * W)
#define INF_SQ 524289.0f  // H*H + W*W + 1, matches reference INF
#define K2_BLOCKS 256     // 2 rows per block; 1 block/CU -> co-residency safe

// ws layout: d1[N] floats | colmax[W] floats | ctl[2] uints (counter, maxd bits)

// K1: one block per column c. Nearest-zero via per-wave ballot masks.
//   d1[i][c] = nd^2 (nd = distance to nearest zero in column), INF_SQ if none.
//   colmax[c] = max over rows of masks[.][c]. Block 0 re-arms K2's ctl scalars.
__global__ __launch_bounds__(512)
void colscan_k(const float* __restrict__ masks, float* __restrict__ d1,
               float* __restrict__ colmax, unsigned int* __restrict__ ctl) {
    const int c = blockIdx.x;
    const int t = threadIdx.x;      // row
    const int w = t >> 6, lane = t & 63;

    __shared__ unsigned long long smask[8];  // zero-pixel bitmask per wave
    __shared__ float red[8];

    const float v = masks[t * W + c];
    const unsigned long long bal = __ballot(v == 0.0f);
    if (lane == 0) smask[w] = bal;

    float m = v;
    for (int off = 32; off > 0; off >>= 1) m = fmaxf(m, __shfl_down(m, off, 64));
    if (lane == 0) red[w] = m;
    __syncthreads();

    // nearest zero at index <= t
    int prev = -100000;
    {
        const unsigned long long bel = smask[w] << (63 - lane);  // bit t at pos 63
        if (bel) prev = t - __clzll(bel);
        else {
            for (int ww = w - 1; ww >= 0; --ww)
                if (smask[ww]) { prev = (ww << 6) + 63 - __clzll(smask[ww]); break; }
        }
    }
    // nearest zero at index >= t
    int nxt = 100000;
    {
        const unsigned long long abv = smask[w] >> lane;         // bit t at pos 0
        if (abv) nxt = t + (__ffsll((unsigned long long)abv) - 1);
        else {
            for (int ww = w + 1; ww < 8; ++ww)
                if (smask[ww]) { nxt = (ww << 6) + (__ffsll((unsigned long long)smask[ww]) - 1); break; }
        }
    }
    const int nd = min(t - prev, nxt - t);
    d1[t * W + c] = (nd <= H - 1) ? (float)(nd * nd) : INF_SQ;

    if (t == 0) {
        float q = red[0];
        for (int i = 1; i < 8; i++) q = fmaxf(q, red[i]);
        colmax[c] = q;
    }
    // re-arm K2's barrier/max scalars every call (stream-ordered before K2)
    if (c == 0 && t == 0) { ctl[0] = 0u; ctl[1] = 0u; }
}

// K2: 256 blocks, 2 rows each. Exact windowed min-plus, dis kept in registers,
// scalar-only spin barrier for the global maxima, then normalize in-place.
__global__ __launch_bounds__(512)
void rowfin_k(const float* __restrict__ masks, const float* __restrict__ d1,
              const float* __restrict__ colmax, float* __restrict__ out,
              unsigned int* __restrict__ ctl) {
    const int t = threadIdx.x;      // col
    const int r0 = blockIdx.x * 2;

    __shared__ float sr[2][W];
    __shared__ float smr[8], smc[8];

    sr[0][t] = d1[r0 * W + t];
    sr[1][t] = d1[(r0 + 1) * W + t];
    float cm = colmax[t];           // redundant per-block maxm reduce input
    __syncthreads();

    float dreg[2];
#pragma unroll
    for (int rr = 0; rr < 2; ++rr) {
        const float ub = sr[rr][t];
        int R = (int)ceilf(sqrtf(ub));
        for (int off = 32; off > 0; off >>= 1) R = max(R, __shfl_down(R, off, 64));
        R = __shfl(R, 0, 64);       // wave-uniform window (exact: (k-l)^2 > ub can't win)
        if (R > W - 1) R = W - 1;

        float m = ub;
        for (int o = 1; o <= R; ++o) {
            const float oo = (float)o * (float)o;
            const int lm = t - o, lp = t + o;
            const float a = (lm >= 0) ? sr[rr][lm] : 1e30f;
            const float b = (lp < W) ? sr[rr][lp] : 1e30f;
            m = fminf(m, oo + fminf(a, b));
        }
        dreg[rr] = sqrtf(m);
    }

    // block reduce: max(dis) over both rows, and colmax -> maxm
    float r = fmaxf(dreg[0], dreg[1]);
    for (int off = 32; off > 0; off >>= 1) {
        r = fmaxf(r, __shfl_down(r, off, 64));
        cm = fmaxf(cm, __shfl_down(cm, off, 64));
    }
    if ((t & 63) == 0) { smr[t >> 6] = r; smc[t >> 6] = cm; }
    __syncthreads();
    if (t == 0) {
        for (int i = 1; i < 8; i++) { r = fmaxf(r, smr[i]); cm = fmaxf(cm, smc[i]); }
        smc[0] = cm;
        atomicMax(ctl + 1, __float_as_uint(r));  // device-scope, relaxed
        // arrive with release (orders the atomicMax before the count)
        __hip_atomic_fetch_add(ctl, 1u, __ATOMIC_ACQ_REL, __HIP_MEMORY_SCOPE_AGENT);
        // scalar-only spin: wait for all 256 blocks
        while (__hip_atomic_load(ctl, __ATOMIC_ACQUIRE, __HIP_MEMORY_SCOPE_AGENT) < K2_BLOCKS) {
            __builtin_amdgcn_s_sleep(1);
        }
        smr[0] = __uint_as_float(
            __hip_atomic_load(ctl + 1, __ATOMIC_ACQUIRE, __HIP_MEMORY_SCOPE_AGENT));
    }
    __syncthreads();
    const float maxm = smc[0];
    const float maxd = smr[0];

#pragma unroll
    for (int rr = 0; rr < 2; ++rr) {
        const int i = (r0 + rr) * W + t;
        const float sk = dreg[rr] / maxd;
        out[i] = sk;                        // skeleton
        out[N + i] = masks[i] / maxm - sk;  // boundary
    }
}

extern "C" void kernel_launch(void* const* d_in, const int* in_sizes, int n_in,
                              void* d_out, int out_size, void* d_ws, size_t ws_size,
                              hipStream_t stream) {
    const float* masks = (const float*)d_in[0];
    float* out = (float*)d_out;
    float* d1 = (float*)d_ws;            // N floats
    float* colmax = d1 + N;              // W floats
    unsigned int* ctl = (unsigned int*)(colmax + W);  // counter, maxd bits

    hipLaunchKernelGGL(colscan_k, dim3(W), dim3(512), 0, stream, masks, d1, colmax, ctl);
    hipLaunchKernelGGL(rowfin_k, dim3(K2_BLOCKS), dim3(512), 0, stream, masks, d1, colmax, out, ctl);
}

// Round 7
// 19.286 us; speedup vs baseline: 1.5812x; 1.5812x over previous
//
#include <hip/hip_runtime.h>

#define H 512
#define W 512
#define N (H * W)
#define INF_SQ 524289.0f  // H*H + W*W + 1, matches reference INF
#define CG 16             // columns per K1 block
#define K1_BLOCKS (W / CG)

// K1: 32 blocks x 16 columns. Coalesced load -> padded LDS transpose ->
// per-wave ballot masks -> nearest-zero distance^2 -> coalesced store.
//   d1[i][c] = nd^2 (nd = distance to nearest zero in column), INF_SQ if none.
//   blockmax[b] = max of masks over the block's tile (partial for maxm).
__global__ __launch_bounds__(512)
void colscan_k(const float* __restrict__ masks, float* __restrict__ d1,
               float* __restrict__ blockmax) {
    const int b = blockIdx.x;
    const int c0 = b * CG;
    const int t = threadIdx.x;      // row for the scan phase
    const int w = t >> 6, lane = t & 63;

    __shared__ float tile[H][CG + 1];                 // +1 pad: 2-way LDS conflicts only
    __shared__ unsigned long long smask[CG][8];       // zero-bitmask per column per wave
    __shared__ float red[8];

    // coalesced load (64 consecutive lanes = 4 rows x 16 cols, 64B segments)
    float tmax = 0.0f;
#pragma unroll
    for (int i = 0; i < CG; ++i) {
        const int f = t + 512 * i;
        const int row = f >> 4;
        const int col = f & 15;
        const float v = masks[row * W + c0 + col];
        tile[row][col] = v;
        tmax = fmaxf(tmax, v);
    }
    for (int off = 32; off > 0; off >>= 1) tmax = fmaxf(tmax, __shfl_down(tmax, off, 64));
    if (lane == 0) red[w] = tmax;
    __syncthreads();

    // one ballot per column (thread t = row t)
#pragma unroll
    for (int j = 0; j < CG; ++j) {
        const unsigned long long bal = __ballot(tile[t][j] == 0.0f);
        if (lane == 0) smask[j][w] = bal;
    }
    __syncthreads();

    // nearest zero above/below via clz/ffs on wave masks; nd^2 back into tile
#pragma unroll
    for (int j = 0; j < CG; ++j) {
        const unsigned long long m = smask[j][w];
        int prev = -100000;
        const unsigned long long bel = m << (63 - lane);   // bit t at pos 63
        if (bel) prev = t - __clzll(bel);
        else {
            for (int ww = w - 1; ww >= 0; --ww)
                if (smask[j][ww]) { prev = (ww << 6) + 63 - __clzll(smask[j][ww]); break; }
        }
        int nxt = 100000;
        const unsigned long long abv = m >> lane;          // bit t at pos 0
        if (abv) nxt = t + (__ffsll(abv) - 1);
        else {
            for (int ww = w + 1; ww < 8; ++ww)
                if (smask[j][ww]) { nxt = (ww << 6) + (__ffsll(smask[j][ww]) - 1); break; }
        }
        const int nd = min(t - prev, nxt - t);
        tile[t][j] = (nd <= H - 1) ? (float)(nd * nd) : INF_SQ;
    }
    __syncthreads();

    // coalesced store
#pragma unroll
    for (int i = 0; i < CG; ++i) {
        const int f = t + 512 * i;
        const int row = f >> 4;
        const int col = f & 15;
        d1[row * W + c0 + col] = tile[row][col];
    }

    if (t == 0) {
        float q = red[0];
        for (int i = 1; i < 8; i++) q = fmaxf(q, red[i]);
        blockmax[b] = q;
    }
}

// K2: one block per row h. Exact WINDOWED min-plus:
//   ub = d1[h][k] (candidate l=k); any l with (k-l)^2 > ub cannot win,
//   so only offsets o <= R = ceil(sqrt(ub)) matter. R wave-maxed for uniformity.
__global__ __launch_bounds__(512)
void rowpass_k(const float* __restrict__ d1, float* __restrict__ dis,
               float* __restrict__ rowmax) {
    const int h = blockIdx.x;
    const int k = threadIdx.x;      // col

    __shared__ float sr[W];
    __shared__ float sm[8];
    sr[k] = d1[h * W + k];
    __syncthreads();

    const float ub = sr[k];
    int R = (int)ceilf(sqrtf(ub));
    for (int off = 32; off > 0; off >>= 1) R = max(R, __shfl_down(R, off, 64));
    R = __shfl(R, 0, 64);           // wave-uniform window
    if (R > W - 1) R = W - 1;       // degenerate (no zero anywhere) safety

    float m = ub;
    for (int o = 1; o <= R; ++o) {
        const float oo = (float)o * (float)o;
        const int lm = k - o, lp = k + o;
        const float a = (lm >= 0) ? sr[lm] : 1e30f;
        const float bb = (lp < W) ? sr[lp] : 1e30f;
        m = fminf(m, oo + fminf(a, bb));
    }
    const float d = sqrtf(m);
    dis[h * W + k] = d;

    float r = d;
    for (int off = 32; off > 0; off >>= 1) r = fmaxf(r, __shfl_down(r, off, 64));
    if ((k & 63) == 0) sm[k >> 6] = r;
    __syncthreads();
    if (k == 0) {
        for (int i = 1; i < 8; i++) r = fmaxf(r, sm[i]);
        rowmax[h] = r;
    }
}

// K3: every block redundantly reduces the 32 blockmax + 512 rowmax partials,
// then normalizes its row.
__global__ __launch_bounds__(512)
void finalize_k(const float* __restrict__ masks,
                const float* __restrict__ blockmax,
                const float* __restrict__ rowmax,
                float* __restrict__ out) {
    const int h = blockIdx.x;
    const int t = threadIdx.x;

    __shared__ float smc[8], smr[8];
    float cm = (t < K1_BLOCKS) ? blockmax[t] : 0.0f;
    float rm = rowmax[t];
    for (int off = 32; off > 0; off >>= 1) {
        cm = fmaxf(cm, __shfl_down(cm, off, 64));
        rm = fmaxf(rm, __shfl_down(rm, off, 64));
    }
    if ((t & 63) == 0) { smc[t >> 6] = cm; smr[t >> 6] = rm; }
    __syncthreads();
    if (t == 0) {
        for (int i = 1; i < 8; i++) { cm = fmaxf(cm, smc[i]); rm = fmaxf(rm, smr[i]); }
        smc[0] = cm; smr[0] = rm;
    }
    __syncthreads();
    const float maxm = smc[0];
    const float maxd = smr[0];

    const int i = h * W + t;
    const float d = out[i];         // dis written by rowpass_k
    const float sk = d / maxd;
    out[i] = sk;                    // skeleton
    out[N + i] = masks[i] / maxm - sk;  // boundary
}

extern "C" void kernel_launch(void* const* d_in, const int* in_sizes, int n_in,
                              void* d_out, int out_size, void* d_ws, size_t ws_size,
                              hipStream_t stream) {
    const float* masks = (const float*)d_in[0];
    float* out = (float*)d_out;
    float* d1 = (float*)d_ws;       // N floats
    float* blockmax = d1 + N;       // K1_BLOCKS floats
    float* rowmax = blockmax + K1_BLOCKS;  // H floats

    hipLaunchKernelGGL(colscan_k, dim3(K1_BLOCKS), dim3(512), 0, stream, masks, d1, blockmax);
    hipLaunchKernelGGL(rowpass_k, dim3(H), dim3(512), 0, stream, d1, out, rowmax);
    hipLaunchKernelGGL(finalize_k, dim3(H), dim3(512), 0, stream, masks, blockmax, rowmax, out);
}

// Round 8
// 16.232 us; speedup vs baseline: 1.8787x; 1.1882x over previous
//
#include <hip/hip_runtime.h>

#define H 512
#define W 512
#define N (H * W)
#define INF_SQ 524289.0f  // H*H + W*W + 1, matches reference INF

// K1: one WAVE per column (128 blocks x 256 threads). Register-only:
// 8 ballots give the column's 512-bit zero-mask in every lane's registers;
// nearest-zero via clz/ffs. No LDS, no barriers.
//   d1[i][c] = nd^2 (nd = distance to nearest zero in column), INF_SQ if none.
//   colmax[c] = max over rows of masks[.][c].
__global__ __launch_bounds__(256)
void colscan_k(const float* __restrict__ masks, float* __restrict__ d1,
               float* __restrict__ colmax) {
    const int lane = threadIdx.x & 63;
    const int c = blockIdx.x * 4 + (threadIdx.x >> 6);  // wave -> column

    float v[8];
    unsigned long long bm[8];
    float m = 0.0f;
#pragma unroll
    for (int i = 0; i < 8; ++i) {
        v[i] = masks[(i * 64 + lane) * W + c];
        m = fmaxf(m, v[i]);
    }
#pragma unroll
    for (int i = 0; i < 8; ++i) bm[i] = __ballot(v[i] == 0.0f);

#pragma unroll
    for (int i = 0; i < 8; ++i) {
        const int r = i * 64 + lane;
        // nearest zero at index <= r
        int prev = -100000;
        const unsigned long long bel = bm[i] << (63 - lane);  // bit r at pos 63
        if (bel) prev = r - __clzll(bel);
        else {
            for (int ww = i - 1; ww >= 0; --ww)
                if (bm[ww]) { prev = (ww << 6) + 63 - __clzll(bm[ww]); break; }
        }
        // nearest zero at index >= r
        int nxt = 100000;
        const unsigned long long abv = bm[i] >> lane;         // bit r at pos 0
        if (abv) nxt = r + (__ffsll(abv) - 1);
        else {
            for (int ww = i + 1; ww < 8; ++ww)
                if (bm[ww]) { nxt = (ww << 6) + (__ffsll(bm[ww]) - 1); break; }
        }
        const int nd = min(r - prev, nxt - r);
        d1[r * W + c] = (nd <= H - 1) ? (float)(nd * nd) : INF_SQ;
    }

    for (int off = 32; off > 0; off >>= 1) m = fmaxf(m, __shfl_down(m, off, 64));
    if (lane == 0) colmax[c] = m;
}

// K2: one block per row h. Exact WINDOWED min-plus:
//   ub = d1[h][k] (candidate l=k); any l with (k-l)^2 > ub cannot win,
//   so only offsets o <= R = ceil(sqrt(ub)) matter. R wave-maxed for uniformity.
__global__ __launch_bounds__(512)
void rowpass_k(const float* __restrict__ d1, float* __restrict__ dis,
               float* __restrict__ rowmax) {
    const int h = blockIdx.x;
    const int k = threadIdx.x;      // col

    __shared__ float sr[W];
    __shared__ float sm[8];
    sr[k] = d1[h * W + k];
    __syncthreads();

    const float ub = sr[k];
    int R = (int)ceilf(sqrtf(ub));
    for (int off = 32; off > 0; off >>= 1) R = max(R, __shfl_down(R, off, 64));
    R = __shfl(R, 0, 64);           // wave-uniform window
    if (R > W - 1) R = W - 1;       // degenerate (no zero anywhere) safety

    float m = ub;
    for (int o = 1; o <= R; ++o) {
        const float oo = (float)o * (float)o;
        const int lm = k - o, lp = k + o;
        const float a = (lm >= 0) ? sr[lm] : 1e30f;
        const float bb = (lp < W) ? sr[lp] : 1e30f;
        m = fminf(m, oo + fminf(a, bb));
    }
    const float d = sqrtf(m);
    dis[h * W + k] = d;

    float r = d;
    for (int off = 32; off > 0; off >>= 1) r = fmaxf(r, __shfl_down(r, off, 64));
    if ((k & 63) == 0) sm[k >> 6] = r;
    __syncthreads();
    if (k == 0) {
        for (int i = 1; i < 8; i++) r = fmaxf(r, sm[i]);
        rowmax[h] = r;
    }
}

// K3: one block per row, float4-vectorized. Every block redundantly reduces
// the 512 colmax + 512 rowmax partials, then normalizes its row.
__global__ __launch_bounds__(128)
void finalize_k(const float* __restrict__ masks,
                const float* __restrict__ colmax,
                const float* __restrict__ rowmax,
                float* __restrict__ out) {
    const int h = blockIdx.x;
    const int t = threadIdx.x;      // 128 threads, 4 cols each

    __shared__ float smc[2], smr[2];
    float cm = fmaxf(fmaxf(colmax[t], colmax[t + 128]),
                     fmaxf(colmax[t + 256], colmax[t + 384]));
    float rm = fmaxf(fmaxf(rowmax[t], rowmax[t + 128]),
                     fmaxf(rowmax[t + 256], rowmax[t + 384]));
    for (int off = 32; off > 0; off >>= 1) {
        cm = fmaxf(cm, __shfl_down(cm, off, 64));
        rm = fmaxf(rm, __shfl_down(rm, off, 64));
    }
    if ((t & 63) == 0) { smc[t >> 6] = cm; smr[t >> 6] = rm; }
    __syncthreads();
    const float maxm = fmaxf(smc[0], smc[1]);
    const float maxd = fmaxf(smr[0], smr[1]);

    const int i = (h * W) / 4 + t;  // float4 index
    const float4 d4 = ((const float4*)out)[i];        // dis from rowpass_k
    const float4 m4 = ((const float4*)masks)[i];
    float4 sk, bd;
    sk.x = d4.x / maxd; sk.y = d4.y / maxd; sk.z = d4.z / maxd; sk.w = d4.w / maxd;
    bd.x = m4.x / maxm - sk.x; bd.y = m4.y / maxm - sk.y;
    bd.z = m4.z / maxm - sk.z; bd.w = m4.w / maxm - sk.w;
    ((float4*)out)[i] = sk;                 // skeleton
    ((float4*)out)[N / 4 + i] = bd;         // boundary
}

extern "C" void kernel_launch(void* const* d_in, const int* in_sizes, int n_in,
                              void* d_out, int out_size, void* d_ws, size_t ws_size,
                              hipStream_t stream) {
    const float* masks = (const float*)d_in[0];
    float* out = (float*)d_out;
    float* d1 = (float*)d_ws;       // N floats
    float* colmax = d1 + N;         // W floats
    float* rowmax = colmax + W;     // H floats

    hipLaunchKernelGGL(colscan_k, dim3(W / 4), dim3(256), 0, stream, masks, d1, colmax);
    hipLaunchKernelGGL(rowpass_k, dim3(H), dim3(512), 0, stream, d1, out, rowmax);
    hipLaunchKernelGGL(finalize_k, dim3(H), dim3(128), 0, stream, masks, colmax, rowmax, out);
}

// Round 9
// 13.431 us; speedup vs baseline: 2.2705x; 1.2085x over previous
//
#include <hip/hip_runtime.h>

#define H 512
#define W 512
#define N (H * W)
#define INF_SQ 524289.0f  // H*H + W*W + 1, matches reference INF
#define KA_BLOCKS 1024    // 256 threads each, 1 pixel/thread
#define KB_BLOCKS 512     // 128 threads each, float4

// K_A: direct 2D EDT via exact Chebyshev ring scan.
//   best(p) = min over zero pixels q of ||p-q||^2; ring r has min d^2 = r^2,
//   so scanning while r^2 < best is exact. Zero pixels skip entirely.
//   Writes dis = sqrt(best) into out[0:N]; per-block partial maxes of masks
//   and dis into pmaxm/pmaxd.
__global__ __launch_bounds__(256)
void edt2d_k(const float* __restrict__ masks, float* __restrict__ dis,
             float* __restrict__ pmaxm, float* __restrict__ pmaxd) {
    const int idx = blockIdx.x * 256 + threadIdx.x;
    const int y = idx >> 9, x = idx & (W - 1);

    const float v = masks[idx];
    float best = (v == 0.0f) ? 0.0f : INF_SQ;

    for (int r = 1; (float)(r * r) < best; ++r) {
        const int rr = r * r;
        const int ym = y - r, yp = y + r;
        const int x0 = max(x - r, 0), x1 = min(x + r, W - 1);
        if (ym >= 0) {
            const float* row = masks + ym * W;
            for (int x2 = x0; x2 <= x1; ++x2)
                if (row[x2] == 0.0f) {
                    const int dx = x2 - x;
                    best = fminf(best, (float)(dx * dx + rr));
                }
        }
        if (yp < H) {
            const float* row = masks + yp * W;
            for (int x2 = x0; x2 <= x1; ++x2)
                if (row[x2] == 0.0f) {
                    const int dx = x2 - x;
                    best = fminf(best, (float)(dx * dx + rr));
                }
        }
        const int y0 = max(y - r + 1, 0), y1 = min(y + r - 1, H - 1);
        if (x - r >= 0) {
            for (int y2 = y0; y2 <= y1; ++y2)
                if (masks[y2 * W + x - r] == 0.0f) {
                    const int dy = y2 - y;
                    best = fminf(best, (float)(dy * dy + rr));
                }
        }
        if (x + r < W) {
            for (int y2 = y0; y2 <= y1; ++y2)
                if (masks[y2 * W + x + r] == 0.0f) {
                    const int dy = y2 - y;
                    best = fminf(best, (float)(dy * dy + rr));
                }
        }
    }

    const float d = sqrtf(best);
    dis[idx] = d;

    // block partial maxes
    float mm = v, md = d;
    for (int off = 32; off > 0; off >>= 1) {
        mm = fmaxf(mm, __shfl_down(mm, off, 64));
        md = fmaxf(md, __shfl_down(md, off, 64));
    }
    __shared__ float sm[4], sd[4];
    const int w = threadIdx.x >> 6, lane = threadIdx.x & 63;
    if (lane == 0) { sm[w] = mm; sd[w] = md; }
    __syncthreads();
    if (threadIdx.x == 0) {
        for (int i = 1; i < 4; ++i) { mm = fmaxf(mm, sm[i]); md = fmaxf(md, sd[i]); }
        pmaxm[blockIdx.x] = mm;
        pmaxd[blockIdx.x] = md;
    }
}

// K_B: every block redundantly reduces the 1024+1024 partials, then
// normalizes its slice (float4).
__global__ __launch_bounds__(128)
void finalize_k(const float* __restrict__ masks,
                const float* __restrict__ pmaxm,
                const float* __restrict__ pmaxd,
                float* __restrict__ out) {
    const int t = threadIdx.x;

    float mm = 0.0f, md = 0.0f;
#pragma unroll
    for (int i = 0; i < KA_BLOCKS / 128; ++i) {
        mm = fmaxf(mm, pmaxm[t + i * 128]);
        md = fmaxf(md, pmaxd[t + i * 128]);
    }
    for (int off = 32; off > 0; off >>= 1) {
        mm = fmaxf(mm, __shfl_down(mm, off, 64));
        md = fmaxf(md, __shfl_down(md, off, 64));
    }
    __shared__ float sm[2], sd[2];
    if ((t & 63) == 0) { sm[t >> 6] = mm; sd[t >> 6] = md; }
    __syncthreads();
    const float maxm = fmaxf(sm[0], sm[1]);
    const float maxd = fmaxf(sd[0], sd[1]);

    const int i = blockIdx.x * 128 + t;  // float4 index; 512*128 = N/4
    const float4 d4 = ((const float4*)out)[i];
    const float4 m4 = ((const float4*)masks)[i];
    float4 sk, bd;
    sk.x = d4.x / maxd; sk.y = d4.y / maxd; sk.z = d4.z / maxd; sk.w = d4.w / maxd;
    bd.x = m4.x / maxm - sk.x; bd.y = m4.y / maxm - sk.y;
    bd.z = m4.z / maxm - sk.z; bd.w = m4.w / maxm - sk.w;
    ((float4*)out)[i] = sk;            // skeleton
    ((float4*)out)[N / 4 + i] = bd;    // boundary
}

extern "C" void kernel_launch(void* const* d_in, const int* in_sizes, int n_in,
                              void* d_out, int out_size, void* d_ws, size_t ws_size,
                              hipStream_t stream) {
    const float* masks = (const float*)d_in[0];
    float* out = (float*)d_out;
    float* pmaxm = (float*)d_ws;          // KA_BLOCKS floats
    float* pmaxd = pmaxm + KA_BLOCKS;     // KA_BLOCKS floats

    hipLaunchKernelGGL(edt2d_k, dim3(KA_BLOCKS), dim3(256), 0, stream, masks, out, pmaxm, pmaxd);
    hipLaunchKernelGGL(finalize_k, dim3(KB_BLOCKS), dim3(128), 0, stream, masks, pmaxm, pmaxd, out);
}

// Round 10
// 12.286 us; speedup vs baseline: 2.4821x; 1.0932x over previous
//
#include <hip/hip_runtime.h>

#define H 512
#define W 512
#define N (H * W)
#define INF_SQ 524289.0f  // H*H + W*W + 1, matches reference INF
#define KA_BLOCKS 1024    // 256 threads each, 1 pixel/thread
#define KB_BLOCKS 512     // 128 threads each, float4

// K_A: direct 2D EDT, branchless ring-1 prologue + exact ring loop for r>=2.
//   best(p) = min over zero pixels q of ||p-q||^2. After ring 1 is scanned,
//   any ring r>=2 has d^2 >= 4, so looping while r^2 < best stays exact.
__global__ __launch_bounds__(256)
void edt2d_k(const float* __restrict__ masks, float* __restrict__ dis,
             float* __restrict__ pmaxm, float* __restrict__ pmaxd) {
    const int idx = blockIdx.x * 256 + threadIdx.x;
    const int y = idx >> 9, x = idx & (W - 1);

    const float v = masks[idx];

    // ---- branchless ring-1: 8 clamped neighbor loads + selects ----
    const int ymo = (y > 0 ? y - 1 : 0) * W;
    const int ypo = (y < H - 1 ? y + 1 : H - 1) * W;
    const int yco = y * W;
    const int xm = (x > 0 ? x - 1 : 0);
    const int xp = (x < W - 1 ? x + 1 : W - 1);
    const bool vy0 = (y > 0), vy1 = (y < H - 1), vx0 = (x > 0), vx1 = (x < W - 1);

    const float n00 = masks[ymo + xm], n01 = masks[ymo + x], n02 = masks[ymo + xp];
    const float n10 = masks[yco + xm],                        n12 = masks[yco + xp];
    const float n20 = masks[ypo + xm], n21 = masks[ypo + x], n22 = masks[ypo + xp];

    float best = INF_SQ;
    best = fminf(best, (vy0 && vx0 && n00 == 0.0f) ? 2.0f : INF_SQ);
    best = fminf(best, (vy0 &&         n01 == 0.0f) ? 1.0f : INF_SQ);
    best = fminf(best, (vy0 && vx1 && n02 == 0.0f) ? 2.0f : INF_SQ);
    best = fminf(best, (vx0 &&         n10 == 0.0f) ? 1.0f : INF_SQ);
    best = fminf(best, (vx1 &&         n12 == 0.0f) ? 1.0f : INF_SQ);
    best = fminf(best, (vy1 && vx0 && n20 == 0.0f) ? 2.0f : INF_SQ);
    best = fminf(best, (vy1 &&         n21 == 0.0f) ? 1.0f : INF_SQ);
    best = fminf(best, (vy1 && vx1 && n22 == 0.0f) ? 2.0f : INF_SQ);
    best = (v == 0.0f) ? 0.0f : best;

    // ---- general exact ring loop, r >= 2 (rarely entered) ----
    for (int r = 2; (float)(r * r) < best; ++r) {
        const int rr = r * r;
        const int ymr = y - r, ypr = y + r;
        const int x0 = max(x - r, 0), x1 = min(x + r, W - 1);
        if (ymr >= 0) {
            const float* row = masks + ymr * W;
            for (int x2 = x0; x2 <= x1; ++x2)
                if (row[x2] == 0.0f) {
                    const int dx = x2 - x;
                    best = fminf(best, (float)(dx * dx + rr));
                }
        }
        if (ypr < H) {
            const float* row = masks + ypr * W;
            for (int x2 = x0; x2 <= x1; ++x2)
                if (row[x2] == 0.0f) {
                    const int dx = x2 - x;
                    best = fminf(best, (float)(dx * dx + rr));
                }
        }
        const int y0 = max(y - r + 1, 0), y1 = min(y + r - 1, H - 1);
        if (x - r >= 0) {
            for (int y2 = y0; y2 <= y1; ++y2)
                if (masks[y2 * W + x - r] == 0.0f) {
                    const int dy = y2 - y;
                    best = fminf(best, (float)(dy * dy + rr));
                }
        }
        if (x + r < W) {
            for (int y2 = y0; y2 <= y1; ++y2)
                if (masks[y2 * W + x + r] == 0.0f) {
                    const int dy = y2 - y;
                    best = fminf(best, (float)(dy * dy + rr));
                }
        }
    }

    const float d = sqrtf(best);
    dis[idx] = d;

    // block partial maxes
    float mm = v, md = d;
    for (int off = 32; off > 0; off >>= 1) {
        mm = fmaxf(mm, __shfl_down(mm, off, 64));
        md = fmaxf(md, __shfl_down(md, off, 64));
    }
    __shared__ float sm[4], sd[4];
    const int w = threadIdx.x >> 6, lane = threadIdx.x & 63;
    if (lane == 0) { sm[w] = mm; sd[w] = md; }
    __syncthreads();
    if (threadIdx.x == 0) {
        for (int i = 1; i < 4; ++i) { mm = fmaxf(mm, sm[i]); md = fmaxf(md, sd[i]); }
        pmaxm[blockIdx.x] = mm;
        pmaxd[blockIdx.x] = md;
    }
}

// K_B: every block redundantly reduces the 1024+1024 partials, then
// normalizes its slice (float4).
__global__ __launch_bounds__(128)
void finalize_k(const float* __restrict__ masks,
                const float* __restrict__ pmaxm,
                const float* __restrict__ pmaxd,
                float* __restrict__ out) {
    const int t = threadIdx.x;

    float mm = 0.0f, md = 0.0f;
#pragma unroll
    for (int i = 0; i < KA_BLOCKS / 128; ++i) {
        mm = fmaxf(mm, pmaxm[t + i * 128]);
        md = fmaxf(md, pmaxd[t + i * 128]);
    }
    for (int off = 32; off > 0; off >>= 1) {
        mm = fmaxf(mm, __shfl_down(mm, off, 64));
        md = fmaxf(md, __shfl_down(md, off, 64));
    }
    __shared__ float sm[2], sd[2];
    if ((t & 63) == 0) { sm[t >> 6] = mm; sd[t >> 6] = md; }
    __syncthreads();
    const float maxm = fmaxf(sm[0], sm[1]);
    const float maxd = fmaxf(sd[0], sd[1]);

    const int i = blockIdx.x * 128 + t;  // float4 index; 512*128 = N/4
    const float4 d4 = ((const float4*)out)[i];
    const float4 m4 = ((const float4*)masks)[i];
    float4 sk, bd;
    sk.x = d4.x / maxd; sk.y = d4.y / maxd; sk.z = d4.z / maxd; sk.w = d4.w / maxd;
    bd.x = m4.x / maxm - sk.x; bd.y = m4.y / maxm - sk.y;
    bd.z = m4.z / maxm - sk.z; bd.w = m4.w / maxm - sk.w;
    ((float4*)out)[i] = sk;            // skeleton
    ((float4*)out)[N / 4 + i] = bd;    // boundary
}

extern "C" void kernel_launch(void* const* d_in, const int* in_sizes, int n_in,
                              void* d_out, int out_size, void* d_ws, size_t ws_size,
                              hipStream_t stream) {
    const float* masks = (const float*)d_in[0];
    float* out = (float*)d_out;
    float* pmaxm = (float*)d_ws;          // KA_BLOCKS floats
    float* pmaxd = pmaxm + KA_BLOCKS;     // KA_BLOCKS floats

    hipLaunchKernelGGL(edt2d_k, dim3(KA_BLOCKS), dim3(256), 0, stream, masks, out, pmaxm, pmaxd);
    hipLaunchKernelGGL(finalize_k, dim3(KB_BLOCKS), dim3(128), 0, stream, masks, pmaxm, pmaxd, out);
}